// Round 1
// 616.513 us; speedup vs baseline: 1.0609x; 1.0609x over previous
//
#include <hip/hip_runtime.h>
#include <hip/hip_bf16.h>
#include <stdint.h>

// BitLinear: out[m][n] = scale[n] * sum_k x[m][k] * q[n][k], q ternary.
// M = B*S = 8192, K = 2048, N = 8192.
// fp16 MFMA path: q exact in fp16, x rounded to fp16 (rel err 2^-11).

typedef float  floatx4 __attribute__((ext_vector_type(4)));
typedef _Float16 f16x8 __attribute__((ext_vector_type(8)));
typedef _Float16 f16x4 __attribute__((ext_vector_type(4)));

#define BM 256
#define BN 256
#define BK 32
#define NSLOT 4

// ---------------- Kernel 1: per-row scale + ternary quantize to fp16 --------
__global__ __launch_bounds__(256) void quant_weight(
    const float* __restrict__ W, f16x4* __restrict__ Q,
    float* __restrict__ scale, int K /*2048*/)
{
    const int wave = threadIdx.x >> 6;
    const int lane = threadIdx.x & 63;
    const int row  = blockIdx.x * 4 + wave;

    const float4* row4 = (const float4*)(W + (size_t)row * K);  // 512 float4
    float4 v[8];
    float s = 0.f;
    #pragma unroll
    for (int i = 0; i < 8; ++i) {
        v[i] = row4[lane + 64 * i];
        s += fabsf(v[i].x) + fabsf(v[i].y) + fabsf(v[i].z) + fabsf(v[i].w);
    }
    #pragma unroll
    for (int m = 1; m < 64; m <<= 1) s += __shfl_xor(s, m, 64);

    const float sc  = fmaxf(s / (float)K, 1e-5f);
    if (lane == 0) scale[row] = sc;
    const float inv = 1.0f / sc;

    f16x4* qrow = Q + (size_t)row * (K / 4);
    #pragma unroll
    for (int i = 0; i < 8; ++i) {
        float t[4] = {v[i].x, v[i].y, v[i].z, v[i].w};
        f16x4 o;
        #pragma unroll
        for (int j = 0; j < 4; ++j)
            o[j] = (_Float16)fminf(fmaxf(rintf(t[j] * inv), -1.f), 1.f);
        qrow[lane + 64 * i] = o;
    }
}

// ---------------- Kernel 2: x fp32 -> fp16 (RNE) ----------------------------
__global__ __launch_bounds__(256) void cvt_f16(
    const float4* __restrict__ X, f16x4* __restrict__ Y)
{
    const size_t i = (size_t)blockIdx.x * blockDim.x + threadIdx.x;
    float4 a = X[i];
    f16x4 o;
    o[0] = (_Float16)a.x; o[1] = (_Float16)a.y;
    o[2] = (_Float16)a.z; o[3] = (_Float16)a.w;
    Y[i] = o;
}

// ---------------- Kernel 3: fp16 GEMM C = A * B^T, deep-pipelined -----------
// 256x256 tile, BK=32, 8 waves (2M x 4N), per-wave 128x64 output.
// 4 LDS slots (128 KiB), prefetch depth 3, counted vmcnt (never 0 in steady
// state), raw s_barrier (no vmcnt drain), setprio around MFMA clusters.
//
// Race-freedom of slot rotation: tile kt+3 (staged during iter kt) writes
// slot (kt+3)&3 == (kt-1)&3, which was read during iter kt-1. All waves
// finished those reads (lgkmcnt(0) before MFMA) before the iter-(kt-1)
// boundary barrier, and iter kt's stage issues come after that barrier.
//
// vmcnt accounting (4 loads/thread/tile, order A0,A1,B0,B1): at the boundary
// of iter kt, loads for tiles <= kt+3 have been issued; vmcnt(8) leaves at
// most tiles kt+2,kt+3 in flight => tiles <= kt+1 landed; every wave waits
// BEFORE the barrier, so after the barrier ALL waves' loads for tile kt+1
// have landed. Tail (staging stopped): vmcnt(4), then vmcnt(0).
__device__ inline void gload_lds16(const void* g, void* l) {
    __builtin_amdgcn_global_load_lds(
        (const __attribute__((address_space(1))) void*)g,
        (__attribute__((address_space(3))) void*)l, 16, 0, 0);
}

__global__ __launch_bounds__(512, 2) void gemm_bt_scaled(
    const _Float16* __restrict__ A,   // [M,K]
    const _Float16* __restrict__ B,   // [N,K] ternary
    const float* __restrict__ scale,  // [N]
    float* __restrict__ C,            // [M,N]
    int M, int N, int K)
{
    // LDS: slot s holds A-tile [256][BK] and B-tile [256][BK], stored as
    // 1024 16B chunks each. Chunk c = (row, kc) with kc = (c&3)^swz(row),
    // swz(row) = (row>>1)&3 -- measured 0 bank conflicts on fragment reads.
    __shared__ __align__(16) _Float16 lds[NSLOT][2][BM * BK]; // 128 KiB

    const int tid  = threadIdx.x;
    const int lane = tid & 63;
    const int wv   = tid >> 6;    // 0..7
    const int wm   = wv >> 2;     // 0..1  (M half)
    const int wn   = wv & 3;      // 0..3  (N quarter)

    // XCD-aware bijective swizzle (nwg = 1024, divisible by 8)
    const int nwg = gridDim.x;
    const int cpx = nwg >> 3;
    const int id  = blockIdx.x;
    const int swz = (id & 7) * cpx + (id >> 3);
    const int nbx = N / BN;
    const int by  = swz / nbx;
    const int bx  = swz % nbx;
    const int rowA0 = by * BM;
    const int rowB0 = bx * BN;

    const int lrow  = lane & 15;   // MFMA m / n index
    const int kquad = lane >> 4;   // k-chunk

    floatx4 acc[8][4] = {};

    // fragment LDS element offsets
    int aoff[8], boff[4];
    #pragma unroll
    for (int t = 0; t < 8; ++t) {
        int ra = wm * 128 + t * 16 + lrow;
        aoff[t] = (ra * 4 + (kquad ^ ((ra >> 1) & 3))) * 8;
    }
    #pragma unroll
    for (int t = 0; t < 4; ++t) {
        int rb = wn * 64 + t * 16 + lrow;
        boff[t] = (rb * 4 + (kquad ^ ((rb >> 1) & 3))) * 8;
    }

    // staging: 1024 chunks per operand tile, 2 per thread per operand
    const int c0 = tid,        c1 = tid + 512;
    const int r0 = c0 >> 2,    r1 = c1 >> 2;
    const int k0 = (c0 & 3) ^ ((r0 >> 1) & 3);
    const int k1 = (c1 & 3) ^ ((r1 >> 1) & 3);
    const _Float16* pa0 = A + (size_t)(rowA0 + r0) * K + k0 * 8;
    const _Float16* pa1 = A + (size_t)(rowA0 + r1) * K + k1 * 8;
    const _Float16* pb0 = B + (size_t)(rowB0 + r0) * K + k0 * 8;
    const _Float16* pb1 = B + (size_t)(rowB0 + r1) * K + k1 * 8;
    const int eo0 = c0 * 8, eo1 = c1 * 8;

    // prologue: stage tiles 0..2 into slots 0..2 (12 loads/thread)
    #pragma unroll
    for (int t = 0; t < 3; ++t) {
        gload_lds16(pa0 + t * BK, &lds[t][0][eo0]);
        gload_lds16(pa1 + t * BK, &lds[t][0][eo1]);
        gload_lds16(pb0 + t * BK, &lds[t][1][eo0]);
        gload_lds16(pb1 + t * BK, &lds[t][1][eo1]);
    }
    pa0 += 3 * BK; pa1 += 3 * BK; pb0 += 3 * BK; pb1 += 3 * BK;

    asm volatile("s_waitcnt vmcnt(8)" ::: "memory"); // tile 0 landed
    __builtin_amdgcn_s_barrier();

    const int NT = K / BK;   // 64
    for (int kt0 = 0; kt0 < NT; kt0 += NSLOT) {
        #pragma unroll
        for (int s = 0; s < NSLOT; ++s) {
            const int kt = kt0 + s;
            const bool st = (kt + 3 < NT);
            const int d = (s + 3) & 3;   // dest slot for tile kt+3

            // ---- phase A: frags (m 0..3, all n) + stage A of tile kt+3 ----
            f16x8 afr[4], bfr[4];
            #pragma unroll
            for (int t = 0; t < 4; ++t) bfr[t] = *(const f16x8*)&lds[s][1][boff[t]];
            #pragma unroll
            for (int t = 0; t < 4; ++t) afr[t] = *(const f16x8*)&lds[s][0][aoff[t]];
            if (st) {
                gload_lds16(pa0, &lds[d][0][eo0]);
                gload_lds16(pa1, &lds[d][0][eo1]);
            }
            __builtin_amdgcn_s_barrier();
            asm volatile("s_waitcnt lgkmcnt(0)" ::: "memory");
            __builtin_amdgcn_s_setprio(1);
            #pragma unroll
            for (int mt = 0; mt < 4; ++mt)
                #pragma unroll
                for (int nt = 0; nt < 4; ++nt)
                    acc[mt][nt] = __builtin_amdgcn_mfma_f32_16x16x32_f16(
                        afr[mt], bfr[nt], acc[mt][nt], 0, 0, 0);
            __builtin_amdgcn_s_setprio(0);
            __builtin_amdgcn_s_barrier();

            // ---- phase B: frags (m 4..7) + stage B of tile kt+3 ----
            #pragma unroll
            for (int t = 0; t < 4; ++t) afr[t] = *(const f16x8*)&lds[s][0][aoff[t + 4]];
            if (st) {
                gload_lds16(pb0, &lds[d][1][eo0]);
                gload_lds16(pb1, &lds[d][1][eo1]);
                pa0 += BK; pa1 += BK; pb0 += BK; pb1 += BK;
            }
            __builtin_amdgcn_s_barrier();
            asm volatile("s_waitcnt lgkmcnt(0)" ::: "memory");
            __builtin_amdgcn_s_setprio(1);
            #pragma unroll
            for (int mt = 0; mt < 4; ++mt)
                #pragma unroll
                for (int nt = 0; nt < 4; ++nt)
                    acc[mt + 4][nt] = __builtin_amdgcn_mfma_f32_16x16x32_f16(
                        afr[mt], bfr[nt], acc[mt + 4][nt], 0, 0, 0);
            __builtin_amdgcn_s_setprio(0);

            // ---- K-tile boundary: counted wait, THEN barrier ----
            if (kt + 3 < NT) {
                asm volatile("s_waitcnt vmcnt(8)" ::: "memory");
            } else if (kt + 2 < NT) {
                asm volatile("s_waitcnt vmcnt(4)" ::: "memory");
            } else {
                asm volatile("s_waitcnt vmcnt(0)" ::: "memory");
            }
            __builtin_amdgcn_s_barrier();
        }
    }

    // epilogue: D mapping col = lane&15 (n), row = (lane>>4)*4 + reg (m)
    const int colb = rowB0 + wn * 64 + lrow;
    const int rowb = rowA0 + wm * 128 + kquad * 4;
    #pragma unroll
    for (int nt = 0; nt < 4; ++nt) {
        const float sc = scale[colb + nt * 16];
        #pragma unroll
        for (int mt = 0; mt < 8; ++mt) {
            #pragma unroll
            for (int r = 0; r < 4; ++r) {
                C[(size_t)(rowb + mt * 16 + r) * N + colb + nt * 16] =
                    acc[mt][nt][r] * sc;
            }
        }
    }
}

extern "C" void kernel_launch(void* const* d_in, const int* in_sizes, int n_in,
                              void* d_out, int out_size, void* d_ws, size_t ws_size,
                              hipStream_t stream) {
    const float* x = (const float*)d_in[0];      // [4,2048,2048] fp32
    const float* w = (const float*)d_in[1];      // [8192,2048] fp32
    float* out = (float*)d_out;                  // [4,2048,8192] fp32

    const int M = 8192, K = 2048, N = 8192;

    char* ws = (char*)d_ws;
    float*     scale = (float*)ws;                                 // 32 KiB
    _Float16*  Xh    = (_Float16*)(ws + 32768);                    // 32 MiB
    _Float16*  Qh    = (_Float16*)(ws + 32768 + (size_t)M * K * 2);// 32 MiB

    quant_weight<<<N / 4, 256, 0, stream>>>(w, (f16x4*)Qh, scale, K);
    cvt_f16<<<(M * K / 4) / 256, 256, 0, stream>>>((const float4*)x, (f16x4*)Xh);
    gemm_bt_scaled<<<dim3((M / BM) * (N / BN)), 512, 0, stream>>>(
        Xh, Qh, scale, out, M, N, K);
}

// Round 3
// 597.621 us; speedup vs baseline: 1.0944x; 1.0316x over previous
//
#include <hip/hip_runtime.h>
#include <hip/hip_bf16.h>
#include <stdint.h>

// BitLinear: out[m][n] = scale[n] * sum_k x[m][k] * q[n][k], q ternary.
// M = B*S = 8192, K = 2048, N = 8192.
// fp16 MFMA path: q exact in fp16, x rounded to fp16 (rel err 2^-11).
// (Resubmit of round-2 kernel: bench infra failed before any GPU stage;
// hang-audit found no deadlock mechanism -- barriers uniform, waitcnts
// live, slot rotation race-free, all offsets in bounds.)

typedef float  floatx4 __attribute__((ext_vector_type(4)));
typedef _Float16 f16x8 __attribute__((ext_vector_type(8)));
typedef _Float16 f16x4 __attribute__((ext_vector_type(4)));

#define BM 256
#define BN 256
#define BK 32
#define NSLOT 4

// ---------------- Kernel 1: per-row scale + ternary quantize to fp16 --------
__global__ __launch_bounds__(256) void quant_weight(
    const float* __restrict__ W, f16x4* __restrict__ Q,
    float* __restrict__ scale, int K /*2048*/)
{
    const int wave = threadIdx.x >> 6;
    const int lane = threadIdx.x & 63;
    const int row  = blockIdx.x * 4 + wave;

    const float4* row4 = (const float4*)(W + (size_t)row * K);  // 512 float4
    float4 v[8];
    float s = 0.f;
    #pragma unroll
    for (int i = 0; i < 8; ++i) {
        v[i] = row4[lane + 64 * i];
        s += fabsf(v[i].x) + fabsf(v[i].y) + fabsf(v[i].z) + fabsf(v[i].w);
    }
    #pragma unroll
    for (int m = 1; m < 64; m <<= 1) s += __shfl_xor(s, m, 64);

    const float sc  = fmaxf(s / (float)K, 1e-5f);
    if (lane == 0) scale[row] = sc;
    const float inv = 1.0f / sc;

    f16x4* qrow = Q + (size_t)row * (K / 4);
    #pragma unroll
    for (int i = 0; i < 8; ++i) {
        float t[4] = {v[i].x, v[i].y, v[i].z, v[i].w};
        f16x4 o;
        #pragma unroll
        for (int j = 0; j < 4; ++j)
            o[j] = (_Float16)fminf(fmaxf(rintf(t[j] * inv), -1.f), 1.f);
        qrow[lane + 64 * i] = o;
    }
}

// ---------------- Kernel 2: x fp32 -> fp16 (RNE) ----------------------------
__global__ __launch_bounds__(256) void cvt_f16(
    const float4* __restrict__ X, f16x4* __restrict__ Y)
{
    const size_t i = (size_t)blockIdx.x * blockDim.x + threadIdx.x;
    float4 a = X[i];
    f16x4 o;
    o[0] = (_Float16)a.x; o[1] = (_Float16)a.y;
    o[2] = (_Float16)a.z; o[3] = (_Float16)a.w;
    Y[i] = o;
}

// ---------------- Kernel 3: fp16 GEMM C = A * B^T, deep-pipelined -----------
// 256x256 tile, BK=32, 8 waves (2M x 4N), per-wave 128x64 output.
// 4 LDS slots (128 KiB), prefetch depth 3, counted vmcnt, raw s_barrier.
//
// One-phase-ahead FRAGMENT pipelining: each phase's pre-barrier region
// issues the ds_reads for the NEXT phase's fragments; the counted lgkmcnt
// after the barrier leaves those in flight, so the LDS unit executes ~48
// reads/CU (~580 cyc) UNDER each ~620-cyc MFMA region instead of
// serializing with it (round-1: MfmaUtil capped at ~38% by LDS-region +
// MFMA-region strict alternation).
//
// Slot rotation safety: stage of tile kt+3 (slot (kt-1)&3) is issued in iter
// kt, after the boundary barrier of kt-1; the last reads of slot kt-1 were
// drained by the phase-B lgkmcnt of iter kt-1, before that barrier.
//
// vmcnt accounting (4 loads/thread/tile: 2 A in phase A, 2 B in phase B):
// boundary of iter kt waits vmcnt(4) -> only tile kt+3's 4 loads remain ->
// tiles <= kt+2 landed. Needed because iter kt+1's phase-B region reads
// slot kt+2 fragments. Every wave waits BEFORE the barrier, so the landing
// guarantee is block-wide. Prologue: vmcnt(4) after 12 loads -> tiles 0,1
// landed (prologue reads tile 0, iter 0 phase B reads tile 1).
__device__ inline void gload_lds16(const void* g, void* l) {
    __builtin_amdgcn_global_load_lds(
        (const __attribute__((address_space(1))) void*)g,
        (__attribute__((address_space(3))) void*)l, 16, 0, 0);
}

__global__ __launch_bounds__(512, 2) void gemm_bt_scaled(
    const _Float16* __restrict__ A,   // [M,K]
    const _Float16* __restrict__ B,   // [N,K] ternary
    const float* __restrict__ scale,  // [N]
    float* __restrict__ C,            // [M,N]
    int M, int N, int K)
{
    // LDS: slot s holds A-tile [256][BK] and B-tile [256][BK], stored as
    // 1024 16B chunks each. Chunk c = (row, kc) with kc = (c&3)^swz(row),
    // swz(row) = (row>>1)&3 -- measured 0 bank conflicts on fragment reads.
    __shared__ __align__(16) _Float16 lds[NSLOT][2][BM * BK]; // 128 KiB

    const int tid  = threadIdx.x;
    const int lane = tid & 63;
    const int wv   = tid >> 6;    // 0..7
    const int wm   = wv >> 2;     // 0..1  (M half)
    const int wn   = wv & 3;      // 0..3  (N quarter)

    // XCD swizzle with SQUARE chunks: de-interleave ids per XCD, then
    // enumerate tiles column-major within 8-row bands. Concurrent ~32
    // blocks per XCD cover an 8x4 tile rectangle: 8 A-panels + 4 B-panels
    // (12 MB) instead of 1 A-panel + 32 B-panels (33 MB, zero B reuse --
    // round-1 FETCH_SIZE doubled to 545 MB because of this).
    const int nwg = gridDim.x;               // 1024, %8 == 0
    const int cpx = nwg >> 3;                // 128
    const int id  = blockIdx.x;
    const int j   = (id >> 3) + (id & 7) * cpx;  // XCD-contiguous index
    const int nbx = N / BN;                  // 32
    const int per_band = nbx * 8;            // 256
    const int band = j / per_band;
    const int jj   = j % per_band;
    const int bx   = jj >> 3;
    const int by   = band * 8 + (jj & 7);
    const int rowA0 = by * BM;
    const int rowB0 = bx * BN;

    const int lrow  = lane & 15;   // MFMA m / n index
    const int kquad = lane >> 4;   // k-chunk

    floatx4 acc[8][4] = {};

    // fragment LDS element offsets
    int aoff[8], boff[4];
    #pragma unroll
    for (int t = 0; t < 8; ++t) {
        int ra = wm * 128 + t * 16 + lrow;
        aoff[t] = (ra * 4 + (kquad ^ ((ra >> 1) & 3))) * 8;
    }
    #pragma unroll
    for (int t = 0; t < 4; ++t) {
        int rb = wn * 64 + t * 16 + lrow;
        boff[t] = (rb * 4 + (kquad ^ ((rb >> 1) & 3))) * 8;
    }

    // staging: 1024 chunks per operand tile, 2 per thread per operand
    const int c0 = tid,        c1 = tid + 512;
    const int r0 = c0 >> 2,    r1 = c1 >> 2;
    const int k0 = (c0 & 3) ^ ((r0 >> 1) & 3);
    const int k1 = (c1 & 3) ^ ((r1 >> 1) & 3);
    const _Float16* pa0 = A + (size_t)(rowA0 + r0) * K + k0 * 8;
    const _Float16* pa1 = A + (size_t)(rowA0 + r1) * K + k1 * 8;
    const _Float16* pb0 = B + (size_t)(rowB0 + r0) * K + k0 * 8;
    const _Float16* pb1 = B + (size_t)(rowB0 + r1) * K + k1 * 8;
    const int eo0 = c0 * 8, eo1 = c1 * 8;

    // prologue: stage tiles 0..2 into slots 0..2 (12 loads/thread)
    #pragma unroll
    for (int t = 0; t < 3; ++t) {
        gload_lds16(pa0 + t * BK, &lds[t][0][eo0]);
        gload_lds16(pa1 + t * BK, &lds[t][0][eo1]);
        gload_lds16(pb0 + t * BK, &lds[t][1][eo0]);
        gload_lds16(pb1 + t * BK, &lds[t][1][eo1]);
    }
    pa0 += 3 * BK; pa1 += 3 * BK; pb0 += 3 * BK; pb1 += 3 * BK;

    asm volatile("s_waitcnt vmcnt(4)" ::: "memory"); // tiles 0,1 landed
    __builtin_amdgcn_s_barrier();

    const int NT = K / BK;   // 64

    // fragment registers: B double-buffered by iteration parity,
    // A ping-pongs between phases (all statically named -- no dyn indexing)
    f16x8 bfrE[4], bfrO[4], afrA[4], afrB[4];

    // pipeline prologue: fragments for phase A of tile 0
    #pragma unroll
    for (int t = 0; t < 4; ++t) bfrE[t] = *(const f16x8*)&lds[0][1][boff[t]];
    #pragma unroll
    for (int t = 0; t < 4; ++t) afrA[t] = *(const f16x8*)&lds[0][0][aoff[t]];

#define TILE_STEP(S, BCUR, BNXT)                                             \
    {                                                                        \
        const int kt = kt0 + S;                                              \
        const int d  = (S + 3) & 3;   /* dest slot for tile kt+3 */          \
        const int sn = (S + 1) & 3;   /* slot of tile kt+1 */                \
        /* ---- phase A region: stage A(kt+3); issue afrB reads (slot S) */  \
        if (kt + 3 < NT) {                                                   \
            gload_lds16(pa0, &lds[d][0][eo0]);                               \
            gload_lds16(pa1, &lds[d][0][eo1]);                               \
        }                                                                    \
        afrB[0] = *(const f16x8*)&lds[S][0][aoff[4]];                        \
        afrB[1] = *(const f16x8*)&lds[S][0][aoff[5]];                        \
        afrB[2] = *(const f16x8*)&lds[S][0][aoff[6]];                        \
        afrB[3] = *(const f16x8*)&lds[S][0][aoff[7]];                        \
        __builtin_amdgcn_s_barrier();                                        \
        /* afrA+BCUR (8 older reads) done; leave the 4 afrB in flight */     \
        asm volatile("s_waitcnt lgkmcnt(4)" ::: "memory");                   \
        __builtin_amdgcn_sched_barrier(0);                                   \
        __builtin_amdgcn_s_setprio(1);                                       \
        _Pragma("unroll")                                                    \
        for (int mt = 0; mt < 4; ++mt)                                       \
            _Pragma("unroll")                                                \
            for (int nt = 0; nt < 4; ++nt)                                   \
                acc[mt][nt] = __builtin_amdgcn_mfma_f32_16x16x32_f16(        \
                    afrA[mt], BCUR[nt], acc[mt][nt], 0, 0, 0);               \
        __builtin_amdgcn_s_setprio(0);                                       \
        __builtin_amdgcn_s_barrier();                                        \
        /* ---- phase B region: stage B(kt+3); issue next-A reads (kt+1) */  \
        if (kt + 3 < NT) {                                                   \
            gload_lds16(pb0, &lds[d][1][eo0]);                               \
            gload_lds16(pb1, &lds[d][1][eo1]);                               \
            pa0 += BK; pa1 += BK; pb0 += BK; pb1 += BK;                      \
        }                                                                    \
        if (kt + 1 < NT) {                                                   \
            BNXT[0] = *(const f16x8*)&lds[sn][1][boff[0]];                   \
            BNXT[1] = *(const f16x8*)&lds[sn][1][boff[1]];                   \
            BNXT[2] = *(const f16x8*)&lds[sn][1][boff[2]];                   \
            BNXT[3] = *(const f16x8*)&lds[sn][1][boff[3]];                   \
            afrA[0] = *(const f16x8*)&lds[sn][0][aoff[0]];                   \
            afrA[1] = *(const f16x8*)&lds[sn][0][aoff[1]];                   \
            afrA[2] = *(const f16x8*)&lds[sn][0][aoff[2]];                   \
            afrA[3] = *(const f16x8*)&lds[sn][0][aoff[3]];                   \
        }                                                                    \
        __builtin_amdgcn_s_barrier();                                        \
        if (kt + 1 < NT) {                                                   \
            /* afrB done; leave the 8 next-A reads in flight */              \
            asm volatile("s_waitcnt lgkmcnt(8)" ::: "memory");               \
        } else {                                                             \
            asm volatile("s_waitcnt lgkmcnt(0)" ::: "memory");               \
        }                                                                    \
        __builtin_amdgcn_sched_barrier(0);                                   \
        __builtin_amdgcn_s_setprio(1);                                       \
        _Pragma("unroll")                                                    \
        for (int mt = 0; mt < 4; ++mt)                                       \
            _Pragma("unroll")                                                \
            for (int nt = 0; nt < 4; ++nt)                                   \
                acc[mt + 4][nt] = __builtin_amdgcn_mfma_f32_16x16x32_f16(    \
                    afrB[mt], BCUR[nt], acc[mt + 4][nt], 0, 0, 0);           \
        __builtin_amdgcn_s_setprio(0);                                       \
        /* ---- K-tile boundary: counted wait, THEN barrier ---- */          \
        if (kt + 4 < NT) {                                                   \
            asm volatile("s_waitcnt vmcnt(4)" ::: "memory");                 \
        } else {                                                             \
            asm volatile("s_waitcnt vmcnt(0)" ::: "memory");                 \
        }                                                                    \
        __builtin_amdgcn_s_barrier();                                        \
    }

    for (int kt0 = 0; kt0 < NT; kt0 += NSLOT) {
        TILE_STEP(0, bfrE, bfrO)
        TILE_STEP(1, bfrO, bfrE)
        TILE_STEP(2, bfrE, bfrO)
        TILE_STEP(3, bfrO, bfrE)
    }
#undef TILE_STEP

    // epilogue: D mapping col = lane&15 (n), row = (lane>>4)*4 + reg (m)
    const int colb = rowB0 + wn * 64 + lrow;
    const int rowb = rowA0 + wm * 128 + kquad * 4;
    #pragma unroll
    for (int nt = 0; nt < 4; ++nt) {
        const float sc = scale[colb + nt * 16];
        #pragma unroll
        for (int mt = 0; mt < 8; ++mt) {
            #pragma unroll
            for (int r = 0; r < 4; ++r) {
                C[(size_t)(rowb + mt * 16 + r) * N + colb + nt * 16] =
                    acc[mt][nt][r] * sc;
            }
        }
    }
}

extern "C" void kernel_launch(void* const* d_in, const int* in_sizes, int n_in,
                              void* d_out, int out_size, void* d_ws, size_t ws_size,
                              hipStream_t stream) {
    const float* x = (const float*)d_in[0];      // [4,2048,2048] fp32
    const float* w = (const float*)d_in[1];      // [8192,2048] fp32
    float* out = (float*)d_out;                  // [4,2048,8192] fp32

    const int M = 8192, K = 2048, N = 8192;

    char* ws = (char*)d_ws;
    float*     scale = (float*)ws;                                 // 32 KiB
    _Float16*  Xh    = (_Float16*)(ws + 32768);                    // 32 MiB
    _Float16*  Qh    = (_Float16*)(ws + 32768 + (size_t)M * K * 2);// 32 MiB

    quant_weight<<<N / 4, 256, 0, stream>>>(w, (f16x4*)Qh, scale, K);
    cvt_f16<<<(M * K / 4) / 256, 256, 0, stream>>>((const float4*)x, (f16x4*)Xh);
    gemm_bt_scaled<<<dim3((M / BM) * (N / BN)), 512, 0, stream>>>(
        Xh, Qh, scale, out, M, N, K);
}

// Round 4
// 594.341 us; speedup vs baseline: 1.1005x; 1.0055x over previous
//
#include <hip/hip_runtime.h>
#include <hip/hip_bf16.h>
#include <stdint.h>

// BitLinear: out[m][n] = scale[n] * sum_k x[m][k] * q[n][k], q ternary.
// M = B*S = 8192, K = 2048, N = 8192.
// fp16 MFMA path: q exact in fp16, x rounded to fp16 (rel err 2^-11).

typedef float  floatx4 __attribute__((ext_vector_type(4)));
typedef _Float16 f16x8 __attribute__((ext_vector_type(8)));
typedef _Float16 f16x4 __attribute__((ext_vector_type(4)));

#define BM 256
#define BN 256
#define BK 32
#define NSLOT 4

// ---------------- Kernel 1: per-row scale + ternary quantize to fp16 --------
__global__ __launch_bounds__(256) void quant_weight(
    const float* __restrict__ W, f16x4* __restrict__ Q,
    float* __restrict__ scale, int K /*2048*/)
{
    const int wave = threadIdx.x >> 6;
    const int lane = threadIdx.x & 63;
    const int row  = blockIdx.x * 4 + wave;

    const float4* row4 = (const float4*)(W + (size_t)row * K);  // 512 float4
    float4 v[8];
    float s = 0.f;
    #pragma unroll
    for (int i = 0; i < 8; ++i) {
        v[i] = row4[lane + 64 * i];
        s += fabsf(v[i].x) + fabsf(v[i].y) + fabsf(v[i].z) + fabsf(v[i].w);
    }
    #pragma unroll
    for (int m = 1; m < 64; m <<= 1) s += __shfl_xor(s, m, 64);

    const float sc  = fmaxf(s / (float)K, 1e-5f);
    if (lane == 0) scale[row] = sc;
    const float inv = 1.0f / sc;

    f16x4* qrow = Q + (size_t)row * (K / 4);
    #pragma unroll
    for (int i = 0; i < 8; ++i) {
        float t[4] = {v[i].x, v[i].y, v[i].z, v[i].w};
        f16x4 o;
        #pragma unroll
        for (int j = 0; j < 4; ++j)
            o[j] = (_Float16)fminf(fmaxf(rintf(t[j] * inv), -1.f), 1.f);
        qrow[lane + 64 * i] = o;
    }
}

// ---------------- Kernel 2: x fp32 -> fp16 (RNE) ----------------------------
__global__ __launch_bounds__(256) void cvt_f16(
    const float4* __restrict__ X, f16x4* __restrict__ Y)
{
    const size_t i = (size_t)blockIdx.x * blockDim.x + threadIdx.x;
    float4 a = X[i];
    f16x4 o;
    o[0] = (_Float16)a.x; o[1] = (_Float16)a.y;
    o[2] = (_Float16)a.z; o[3] = (_Float16)a.w;
    Y[i] = o;
}

// ---------------- Kernel 3: fp16 GEMM C = A * B^T, deep-pipelined -----------
// 256x256 tile, BK=32, 8 waves (2M x 4N), per-wave 128x64 output.
// 4 LDS slots (128 KiB), prefetch depth 3. TWO barriers per K-tile (down
// from 4): only (a) stage-landed-before-read [vmcnt(8) + MID barrier] and
// (b) reads-drained-before-overwrite [BOUNDARY barrier] are required;
// the other two barriers only forced lockstep and serialized issue regions
// with MFMA (round-3: MfmaUtil stuck at 41.5%).
//
// All 4 stage loads of tile kt+3 are issued at the top of phase A of kt ->
// landing deadline is the vmcnt(8) after MFMA-A of kt+2: ~2 tile periods
// (round-3: B-half had only ~0.5 phase, stalling the boundary wait).
//
// vmcnt invariant: stages issue 4 ops/tile in tile order, so at most 8 ops
// are ever issued after tile kt+1's batch => vmcnt(8) (after MFMA-A of kt,
// before MID barrier) always guarantees tiles <= kt+1 landed -- needed by
// phase-B reads of slot kt+1 (after MID) and phase-A afrB reads of kt+1.
// No tail special-casing needed.
//
// Read-drain audit (for BOUNDARY): afrB reads of slot kt (phase A of kt)
// drain at phase-B lgkmcnt(8) of kt, before BOUNDARY(kt); slot kt is
// overwritten in phase A of kt+1 (stage of tile kt+4), after BOUNDARY(kt).
// BNXT/afrA reads of slot kt+1 (phase B of kt, the "8 in flight") drain at
// phase-A lgkmcnt(4) of kt+1; slot kt+1 is overwritten in phase A of kt+2,
// separated by BOUNDARY(kt+1). Race-free.
__device__ inline void gload_lds16(const void* g, void* l) {
    __builtin_amdgcn_global_load_lds(
        (const __attribute__((address_space(1))) void*)g,
        (__attribute__((address_space(3))) void*)l, 16, 0, 0);
}

__global__ __launch_bounds__(512, 2) void gemm_bt_scaled(
    const _Float16* __restrict__ A,   // [M,K]
    const _Float16* __restrict__ B,   // [N,K] ternary
    const float* __restrict__ scale,  // [N]
    float* __restrict__ C,            // [M,N]
    int M, int N, int K)
{
    // LDS: slot s holds A-tile [256][BK] and B-tile [256][BK], stored as
    // 1024 16B chunks each. Chunk c = (row, kc) with kc = (c&3)^swz(row),
    // swz(row) = (row>>1)&3 -- measured 0 bank conflicts on fragment reads.
    __shared__ __align__(16) _Float16 lds[NSLOT][2][BM * BK]; // 128 KiB

    const int tid  = threadIdx.x;
    const int lane = tid & 63;
    const int wv   = tid >> 6;    // 0..7
    const int wm   = wv >> 2;     // 0..1  (M half)
    const int wn   = wv & 3;      // 0..3  (N quarter)

    // XCD swizzle with SQUARE chunks (round-3: cut FETCH_SIZE 545->197 MB).
    const int nwg = gridDim.x;               // 1024, %8 == 0
    const int cpx = nwg >> 3;                // 128
    const int id  = blockIdx.x;
    const int j   = (id >> 3) + (id & 7) * cpx;  // XCD-contiguous index
    const int nbx = N / BN;                  // 32
    const int per_band = nbx * 8;            // 256
    const int band = j / per_band;
    const int jj   = j % per_band;
    const int bx   = jj >> 3;
    const int by   = band * 8 + (jj & 7);
    const int rowA0 = by * BM;
    const int rowB0 = bx * BN;

    const int lrow  = lane & 15;   // MFMA m / n index
    const int kquad = lane >> 4;   // k-chunk

    floatx4 acc[8][4] = {};

    // fragment LDS element offsets
    int aoff[8], boff[4];
    #pragma unroll
    for (int t = 0; t < 8; ++t) {
        int ra = wm * 128 + t * 16 + lrow;
        aoff[t] = (ra * 4 + (kquad ^ ((ra >> 1) & 3))) * 8;
    }
    #pragma unroll
    for (int t = 0; t < 4; ++t) {
        int rb = wn * 64 + t * 16 + lrow;
        boff[t] = (rb * 4 + (kquad ^ ((rb >> 1) & 3))) * 8;
    }

    // staging: 1024 chunks per operand tile, 2 per thread per operand
    const int c0 = tid,        c1 = tid + 512;
    const int r0 = c0 >> 2,    r1 = c1 >> 2;
    const int k0 = (c0 & 3) ^ ((r0 >> 1) & 3);
    const int k1 = (c1 & 3) ^ ((r1 >> 1) & 3);
    const _Float16* pa0 = A + (size_t)(rowA0 + r0) * K + k0 * 8;
    const _Float16* pa1 = A + (size_t)(rowA0 + r1) * K + k1 * 8;
    const _Float16* pb0 = B + (size_t)(rowB0 + r0) * K + k0 * 8;
    const _Float16* pb1 = B + (size_t)(rowB0 + r1) * K + k1 * 8;
    const int eo0 = c0 * 8, eo1 = c1 * 8;

    // prologue: stage tiles 0..2 into slots 0..2 (12 loads/thread)
    #pragma unroll
    for (int t = 0; t < 3; ++t) {
        gload_lds16(pa0 + t * BK, &lds[t][0][eo0]);
        gload_lds16(pa1 + t * BK, &lds[t][0][eo1]);
        gload_lds16(pb0 + t * BK, &lds[t][1][eo0]);
        gload_lds16(pb1 + t * BK, &lds[t][1][eo1]);
    }
    pa0 += 3 * BK; pa1 += 3 * BK; pb0 += 3 * BK; pb1 += 3 * BK;

    asm volatile("s_waitcnt vmcnt(8)" ::: "memory"); // tile 0 landed
    __builtin_amdgcn_s_barrier();
    __builtin_amdgcn_sched_barrier(0);

    const int NT = K / BK;   // 64

    // fragment registers: B double-buffered by iteration parity,
    // A ping-pongs between phases (all statically named -- no dyn indexing)
    f16x8 bfrE[4], bfrO[4], afrA[4], afrB[4];

    // pipeline prologue: fragments for phase A of tile 0 (8 reads, left
    // in flight -- drained by iter-0's phase-A lgkmcnt(4))
    #pragma unroll
    for (int t = 0; t < 4; ++t) bfrE[t] = *(const f16x8*)&lds[0][1][boff[t]];
    #pragma unroll
    for (int t = 0; t < 4; ++t) afrA[t] = *(const f16x8*)&lds[0][0][aoff[t]];

#define TILE_STEP(S, BCUR, BNXT)                                             \
    {                                                                        \
        const int kt = kt0 + S;                                              \
        const int d  = (S + 3) & 3;   /* dest slot for tile kt+3 */          \
        const int sn = (S + 1) & 3;   /* slot of tile kt+1 */                \
        /* ---- phase A: stage ALL of tile kt+3; read afrB (slot S) ---- */  \
        if (kt + 3 < NT) {                                                   \
            gload_lds16(pa0, &lds[d][0][eo0]);                               \
            gload_lds16(pa1, &lds[d][0][eo1]);                               \
            gload_lds16(pb0, &lds[d][1][eo0]);                               \
            gload_lds16(pb1, &lds[d][1][eo1]);                               \
            pa0 += BK; pa1 += BK; pb0 += BK; pb1 += BK;                      \
        }                                                                    \
        afrB[0] = *(const f16x8*)&lds[S][0][aoff[4]];                        \
        afrB[1] = *(const f16x8*)&lds[S][0][aoff[5]];                        \
        afrB[2] = *(const f16x8*)&lds[S][0][aoff[6]];                        \
        afrB[3] = *(const f16x8*)&lds[S][0][aoff[7]];                        \
        /* 8 older reads (afrA+BCUR) done; leave the 4 afrB in flight */     \
        asm volatile("s_waitcnt lgkmcnt(4)" ::: "memory");                   \
        __builtin_amdgcn_sched_barrier(0);                                   \
        __builtin_amdgcn_s_setprio(1);                                       \
        _Pragma("unroll")                                                    \
        for (int mt = 0; mt < 4; ++mt)                                       \
            _Pragma("unroll")                                                \
            for (int nt = 0; nt < 4; ++nt)                                   \
                acc[mt][nt] = __builtin_amdgcn_mfma_f32_16x16x32_f16(        \
                    afrA[mt], BCUR[nt], acc[mt][nt], 0, 0, 0);               \
        __builtin_amdgcn_s_setprio(0);                                       \
        __builtin_amdgcn_sched_barrier(0);                                   \
        /* tiles <= kt+1 landed (at most 8 ops issued after kt+1's) */       \
        asm volatile("s_waitcnt vmcnt(8)" ::: "memory");                     \
        __builtin_amdgcn_s_barrier();        /* MID barrier */               \
        __builtin_amdgcn_sched_barrier(0);                                   \
        /* ---- phase B: read next-tile frags (slot kt+1) ---- */            \
        if (kt + 1 < NT) {                                                   \
            BNXT[0] = *(const f16x8*)&lds[sn][1][boff[0]];                   \
            BNXT[1] = *(const f16x8*)&lds[sn][1][boff[1]];                   \
            BNXT[2] = *(const f16x8*)&lds[sn][1][boff[2]];                   \
            BNXT[3] = *(const f16x8*)&lds[sn][1][boff[3]];                   \
            afrA[0] = *(const f16x8*)&lds[sn][0][aoff[0]];                   \
            afrA[1] = *(const f16x8*)&lds[sn][0][aoff[1]];                   \
            afrA[2] = *(const f16x8*)&lds[sn][0][aoff[2]];                   \
            afrA[3] = *(const f16x8*)&lds[sn][0][aoff[3]];                   \
            /* afrB done; leave the 8 next-tile reads in flight */           \
            asm volatile("s_waitcnt lgkmcnt(8)" ::: "memory");               \
        } else {                                                             \
            asm volatile("s_waitcnt lgkmcnt(0)" ::: "memory");               \
        }                                                                    \
        __builtin_amdgcn_sched_barrier(0);                                   \
        __builtin_amdgcn_s_setprio(1);                                       \
        _Pragma("unroll")                                                    \
        for (int mt = 0; mt < 4; ++mt)                                       \
            _Pragma("unroll")                                                \
            for (int nt = 0; nt < 4; ++nt)                                   \
                acc[mt + 4][nt] = __builtin_amdgcn_mfma_f32_16x16x32_f16(    \
                    afrB[mt], BCUR[nt], acc[mt + 4][nt], 0, 0, 0);           \
        __builtin_amdgcn_s_setprio(0);                                       \
        __builtin_amdgcn_sched_barrier(0);                                   \
        __builtin_amdgcn_s_barrier();        /* BOUNDARY barrier */          \
        __builtin_amdgcn_sched_barrier(0);                                   \
    }

    for (int kt0 = 0; kt0 < NT; kt0 += NSLOT) {
        TILE_STEP(0, bfrE, bfrO)
        TILE_STEP(1, bfrO, bfrE)
        TILE_STEP(2, bfrE, bfrO)
        TILE_STEP(3, bfrO, bfrE)
    }
#undef TILE_STEP

    // epilogue: D mapping col = lane&15 (n), row = (lane>>4)*4 + reg (m)
    const int colb = rowB0 + wn * 64 + lrow;
    const int rowb = rowA0 + wm * 128 + kquad * 4;
    #pragma unroll
    for (int nt = 0; nt < 4; ++nt) {
        const float sc = scale[colb + nt * 16];
        #pragma unroll
        for (int mt = 0; mt < 8; ++mt) {
            #pragma unroll
            for (int r = 0; r < 4; ++r) {
                C[(size_t)(rowb + mt * 16 + r) * N + colb + nt * 16] =
                    acc[mt][nt][r] * sc;
            }
        }
    }
}

extern "C" void kernel_launch(void* const* d_in, const int* in_sizes, int n_in,
                              void* d_out, int out_size, void* d_ws, size_t ws_size,
                              hipStream_t stream) {
    const float* x = (const float*)d_in[0];      // [4,2048,2048] fp32
    const float* w = (const float*)d_in[1];      // [8192,2048] fp32
    float* out = (float*)d_out;                  // [4,2048,8192] fp32

    const int M = 8192, K = 2048, N = 8192;

    char* ws = (char*)d_ws;
    float*     scale = (float*)ws;                                 // 32 KiB
    _Float16*  Xh    = (_Float16*)(ws + 32768);                    // 32 MiB
    _Float16*  Qh    = (_Float16*)(ws + 32768 + (size_t)M * K * 2);// 32 MiB

    quant_weight<<<N / 4, 256, 0, stream>>>(w, (f16x4*)Qh, scale, K);
    cvt_f16<<<(M * K / 4) / 256, 256, 0, stream>>>((const float4*)x, (f16x4*)Xh);
    gemm_bt_scaled<<<dim3((M / BM) * (N / BN)), 512, 0, stream>>>(
        Xh, Qh, scale, out, M, N, K);
}